// Round 8
// baseline (48.367 us; speedup 1.0000x reference)
//
#include <hip/hip_runtime.h>

namespace {
constexpr int B_ = 32, S_ = 8, T_ = 128, D_ = 768, A_ = 8, L_ = 8;
constexpr int BS = B_ * S_;                 // 256
constexpr int MEAN_ELEMS = BS * D_;         // 196608
constexpr int EXT_ELEMS  = BS * A_ * D_;    // 1572864
constexpr int D4 = D_ / 4;                  // 192 float4 per row
constexpr int MEAN_BLOCKS = BS;             // one per (b,s)
constexpr int EXT_BLOCKS  = BS * A_;        // 2048: one per (b,s,a), all 3 extracts
constexpr int NTHR = 192;                   // one float4 column per thread

typedef float f32x4 __attribute__((ext_vector_type(4)));  // native vector for nt builtins

__device__ inline f32x4 nt_load(const f32x4* p) {
    return __builtin_nontemporal_load(p);
}
__device__ inline void nt_store(f32x4* p, f32x4 v) {
    __builtin_nontemporal_store(v, p);
}

// Single dispatch; all emb reads are non-temporal (global_load_dwordx4 nt)
// to bypass L1 allocation/miss-tracking: the stream has zero L1 reuse and
// five prior geometries all capped at ~2.1 TB/s consistent with a per-CU
// L1 outstanding-miss limit (~4 KB in flight / CU).
__global__ void __launch_bounds__(NTHR) srl_one(
    const float* __restrict__ emb,
    const int* __restrict__ sids,
    const int* __restrict__ pred,
    const int* __restrict__ arg0,
    const int* __restrict__ arg1,
    float* __restrict__ out)
{
    const int blk = blockIdx.x;
    const int tid = threadIdx.x;

    if (blk < MEAN_BLOCKS) {
        const int bs = blk;
        const f32x4* p = reinterpret_cast<const f32x4*>(emb + (size_t)bs * T_ * D_) + tid;
        f32x4 acc = {0.f, 0.f, 0.f, 0.f};
        #pragma unroll 16
        for (int t = 0; t < T_; ++t) {
            acc += nt_load(p + (size_t)t * D4);
        }
        acc *= (1.0f / T_);
        nt_store(reinterpret_cast<f32x4*>(out) + (size_t)bs * D4 + tid, acc);
        return;
    }

    // ---- extract: one block per (bs, a), all 3 extracts, float4 columns ----
    const int eblk = blk - MEAN_BLOCKS;
    const int bs = eblk >> 3, a = eblk & 7;
    constexpr int NT = 3 * L_;                            // 24 tokens
    __shared__ int toks[NT];
    __shared__ int pos[NT];
    __shared__ float invs[3];

    if (tid < NT) {
        int e = tid >> 3, l = tid & 7;
        const int* p = (e == 0) ? pred : ((e == 1) ? arg0 : arg1);
        toks[tid] = p[(size_t)(bs * A_ + a) * L_ + l];
        pos[tid] = -1;
    }
    __syncthreads();
    if (tid < T_) {
        int id = sids[(size_t)bs * T_ + tid];
        #pragma unroll
        for (int i = 0; i < NT; ++i)
            if (toks[i] != 0 && toks[i] == id) pos[i] = tid;  // ids unique per sentence
    } else if (tid >= 128 && tid < 131) {
        int e = tid - 128, n = 0;
        #pragma unroll
        for (int l = 0; l < L_; ++l) n += (toks[e * L_ + l] != 0);
        invs[e] = 1.0f / (float)(n < 1 ? 1 : n);
    }
    __syncthreads();

    // branch-free: clamp invalid pos to row 0 with weight 0 -> all 24 loads batch
    const f32x4* base4 = reinterpret_cast<const f32x4*>(emb + (size_t)bs * T_ * D_);
    f32x4 acc[3] = {{0.f,0.f,0.f,0.f},{0.f,0.f,0.f,0.f},{0.f,0.f,0.f,0.f}};
    #pragma unroll
    for (int e = 0; e < 3; ++e) {
        #pragma unroll
        for (int l = 0; l < L_; ++l) {
            int p = pos[e * L_ + l];
            float w = (p >= 0) ? 1.0f : 0.0f;
            int pr = (p >= 0) ? p : 0;
            f32x4 v = nt_load(base4 + (size_t)pr * D4 + tid);
            acc[e] += w * v;
        }
    }
    #pragma unroll
    for (int e = 0; e < 3; ++e) {
        f32x4 r = acc[e] * invs[e];
        nt_store(reinterpret_cast<f32x4*>(out + MEAN_ELEMS + (size_t)e * EXT_ELEMS
                                          + (size_t)(bs * A_ + a) * D_) + tid, r);
    }
}
} // namespace

extern "C" void kernel_launch(void* const* d_in, const int* in_sizes, int n_in,
                              void* d_out, int out_size, void* d_ws, size_t ws_size,
                              hipStream_t stream) {
    const float* emb  = (const float*)d_in[0];
    const int*   sids = (const int*)d_in[1];
    const int*   pred = (const int*)d_in[2];
    const int*   arg0 = (const int*)d_in[3];
    const int*   arg1 = (const int*)d_in[4];
    float* out = (float*)d_out;

    srl_one<<<dim3(MEAN_BLOCKS + EXT_BLOCKS), dim3(NTHR), 0, stream>>>(
        emb, sids, pred, arg0, arg1, out);
}

// Round 9
// 42.573 us; speedup vs baseline: 1.1361x; 1.1361x over previous
//
#include <hip/hip_runtime.h>

namespace {
constexpr int T_ = 128, D_ = 768, A_ = 8;
constexpr int BS = 256;                    // B*S
constexpr int D2 = D_ / 2;                 // 384 float2 per row
constexpr int CH = D2 / 2;                 // 192 float2 per half
constexpr int MEAN_F2 = BS * D2;           // 98304
constexpr int EXT_F2  = BS * A_ * D2;      // 786432
constexpr int NTHR = 384;                  // 2 T-groups x 192 lanes
constexpr int NBLK = BS * 2;               // (bs, D-half)

// One-pass weighted-sum: per (bs, D-half) block, stream the sentence slab once,
// accumulating mean + all 24 extract outputs as nibble-weighted sums.
// emb is read exactly once (~100 MB total vs ~247 MB in the gather design).
__global__ void __launch_bounds__(NTHR, 3) srl_ws(
    const float* __restrict__ emb,
    const int* __restrict__ sids,
    const int* __restrict__ pred,
    const int* __restrict__ arg0,
    const int* __restrict__ arg1,
    float* __restrict__ out)
{
    const int blk  = blockIdx.x;
    const int bs   = blk >> 1, half = blk & 1;
    const int tid  = threadIdx.x;
    const int g    = (tid >= CH) ? 1 : 0;   // T-group: rows [g*64, g*64+64)
    const int lt   = tid - g * CH;          // lane's float2 column within half

    __shared__ int      toks[192];          // [e][a][l]
    __shared__ unsigned wrd[T_][4];         // [t]: 3 nibble-words (8 counts ea) + meta
    __shared__ float    invs[24];
    __shared__ float2   comb[25][CH];       // group-1 partials

    if (tid < 192) {
        int e = tid >> 6, r = tid & 63;     // r = a*8 + l
        const int* p = (e == 0) ? pred : ((e == 1) ? arg0 : arg1);
        toks[tid] = p[bs * 64 + r];
    }
    __syncthreads();

    if (tid < T_) {
        // build row t's weight nibbles: count of token matches per output
        int sid = sids[bs * T_ + tid];
        unsigned meta = 0;
        #pragma unroll
        for (int e = 0; e < 3; ++e) {
            unsigned w = 0;
            #pragma unroll
            for (int j = 0; j < 8; ++j) {
                unsigned cnt = 0;
                #pragma unroll
                for (int l = 0; l < 8; ++l) {
                    int tk = toks[e * 64 + j * 8 + l];
                    cnt += (tk != 0 && tk == sid) ? 1u : 0u;
                }
                w |= cnt << (4 * j);        // counts <= 8, fit a nibble
            }
            wrd[tid][e] = w;
            meta |= (w != 0 ? 1u : 0u) << e;
        }
        wrd[tid][3] = meta;
    } else if (tid < 152) {                 // threads 128..151: 1/n_valid
        int o = tid - 128;
        int e = o >> 3, a = o & 7, n = 0;
        #pragma unroll
        for (int l = 0; l < 8; ++l) n += (toks[e * 64 + a * 8 + l] != 0);
        invs[o] = 1.0f / (float)(n < 1 ? 1 : n);
    }
    __syncthreads();

    // ---- stream 64 rows x half-D, accumulate mean + 24 weighted sums ----
    const float2* eb = reinterpret_cast<const float2*>(emb)
                       + (size_t)bs * T_ * D2 + half * CH + lt;
    float2 accm = {0.f, 0.f};
    float2 acc[24];
    #pragma unroll
    for (int o = 0; o < 24; ++o) acc[o] = {0.f, 0.f};

    const int t0 = g * 64;
    float2 vn = eb[(size_t)t0 * D2];
    #pragma unroll 4
    for (int k = 0; k < 64; ++k) {
        const int t = t0 + k;
        float2 v = vn;
        if (k < 63) vn = eb[(size_t)(t + 1) * D2];
        accm.x += v.x; accm.y += v.y;
        unsigned meta = __builtin_amdgcn_readfirstlane(wrd[t][3]);  // uniform
        if (meta) {
            #pragma unroll
            for (int e = 0; e < 3; ++e) {
                if (meta & (1u << e)) {
                    unsigned w = __builtin_amdgcn_readfirstlane(wrd[t][e]);
                    #pragma unroll
                    for (int j = 0; j < 8; ++j) {
                        unsigned c = (w >> (4 * j)) & 15u;
                        if (c) {
                            float fc = (float)c;
                            acc[e * 8 + j].x += fc * v.x;   // compile-time index
                            acc[e * 8 + j].y += fc * v.y;
                        }
                    }
                }
            }
        }
    }

    // ---- combine the two T-groups via LDS; group 0 writes ----
    if (g == 1) {
        comb[24][lt] = accm;
        #pragma unroll
        for (int o = 0; o < 24; ++o) comb[o][lt] = acc[o];
    }
    __syncthreads();
    if (g == 0) {
        float2* o2 = reinterpret_cast<float2*>(out);
        float2 cm = comb[24][lt];
        const float ms = 1.0f / (float)T_;
        float2 r; r.x = (accm.x + cm.x) * ms; r.y = (accm.y + cm.y) * ms;
        o2[(size_t)bs * D2 + half * CH + lt] = r;
        #pragma unroll
        for (int o = 0; o < 24; ++o) {
            float2 cc = comb[o][lt];
            float iv = invs[o];
            float2 rr; rr.x = (acc[o].x + cc.x) * iv; rr.y = (acc[o].y + cc.y) * iv;
            int e = o >> 3, a = o & 7;
            o2[(size_t)MEAN_F2 + (size_t)e * EXT_F2
               + (size_t)(bs * A_ + a) * D2 + half * CH + lt] = rr;
        }
    }
}
} // namespace

extern "C" void kernel_launch(void* const* d_in, const int* in_sizes, int n_in,
                              void* d_out, int out_size, void* d_ws, size_t ws_size,
                              hipStream_t stream) {
    const float* emb  = (const float*)d_in[0];
    const int*   sids = (const int*)d_in[1];
    const int*   pred = (const int*)d_in[2];
    const int*   arg0 = (const int*)d_in[3];
    const int*   arg1 = (const int*)d_in[4];
    float* out = (float*)d_out;

    srl_ws<<<dim3(NBLK), dim3(NTHR), 0, stream>>>(emb, sids, pred, arg0, arg1, out);
}